// Round 1
// baseline (5124.101 us; speedup 1.0000x reference)
//
#include <hip/hip_runtime.h>

#define HID 64
#define NG 256          // 4*H
#define TSTEPS 1024
#define BPW 8           // batch elements per workgroup
#define TW 512          // threads per workgroup (8 waves)

__device__ __forceinline__ float sigf(float x) {
  return 1.0f / (1.0f + __expf(-x));
}
__device__ __forceinline__ float tanhfast(float x) {
  // tanh(x) = 1 - 2/(1+exp(2x)); saturates correctly at +/-inf
  return 1.0f - 2.0f / (1.0f + __expf(2.0f * x));
}

struct __align__(16) SMem {
  float xin[TSTEPS + 1][BPW];  // transposed input; slot [TSTEPS] holds future-step x
  float h1[BPW][HID];
  float h2[BPW][HID];
  float g1[BPW][NG];
  float g2[BPW][NG];
};

__device__ __forceinline__ float dot8a(const float (&w)[8], const float4& a,
                                       const float4& b, float s0) {
  float s = fmaf(w[0], a.x, s0);
  s = fmaf(w[1], a.y, s);
  s = fmaf(w[2], a.z, s);
  s = fmaf(w[3], a.w, s);
  s = fmaf(w[4], b.x, s);
  s = fmaf(w[5], b.y, s);
  s = fmaf(w[6], b.z, s);
  s = fmaf(w[7], b.w, s);
  return s;
}

// Reduce-scatter over the 8-lane column octet (lanes differing in low 3 bits).
// Input: a[b][r] partials. Output: out[r] = sum over octet of a[cg][r].
// All static register indices; selection via per-lane ternary (v_cndmask).
__device__ __forceinline__ void rscat8(const float (&a)[8][4], float (&out)[4],
                                       int cg) {
  float p[8][4];
#pragma unroll
  for (int b = 0; b < 8; ++b)
#pragma unroll
    for (int r = 0; r < 4; ++r) p[b][r] = __shfl_xor(a[b][r], 1, 64);
  const bool s0 = (cg & 1) != 0;
  float t1[4][4];
#pragma unroll
  for (int k = 0; k < 4; ++k)
#pragma unroll
    for (int r = 0; r < 4; ++r) {
      float e = a[2 * k][r] + p[2 * k][r];
      float o = a[2 * k + 1][r] + p[2 * k + 1][r];
      t1[k][r] = s0 ? o : e;
    }
  float p1[4][4];
#pragma unroll
  for (int k = 0; k < 4; ++k)
#pragma unroll
    for (int r = 0; r < 4; ++r) p1[k][r] = __shfl_xor(t1[k][r], 2, 64);
  const bool s1 = (cg & 2) != 0;
  float t2[2][4];
#pragma unroll
  for (int k = 0; k < 2; ++k)
#pragma unroll
    for (int r = 0; r < 4; ++r) {
      float e = t1[2 * k][r] + p1[2 * k][r];
      float o = t1[2 * k + 1][r] + p1[2 * k + 1][r];
      t2[k][r] = s1 ? o : e;
    }
  float p2[2][4];
#pragma unroll
  for (int k = 0; k < 2; ++k)
#pragma unroll
    for (int r = 0; r < 4; ++r) p2[k][r] = __shfl_xor(t2[k][r], 4, 64);
  const bool s2 = (cg & 4) != 0;
#pragma unroll
  for (int r = 0; r < 4; ++r) {
    float e = t2[0][r] + p2[0][r];
    float o = t2[1][r] + p2[1][r];
    out[r] = s2 ? o : e;
  }
}

__global__ __launch_bounds__(TW, 2) void lstm2_kernel(
    const float* __restrict__ input, const float* __restrict__ Wih1,
    const float* __restrict__ Whh1, const float* __restrict__ bih1,
    const float* __restrict__ bhh1, const float* __restrict__ Wih2,
    const float* __restrict__ Whh2, const float* __restrict__ bih2,
    const float* __restrict__ bhh2, const float* __restrict__ Wl,
    const float* __restrict__ bl, const int* __restrict__ future,
    float* __restrict__ out) {
  __shared__ SMem s;
  const int tid = threadIdx.x;
  const int cg = tid & 7;        // column group: cols cg*8 .. cg*8+7
  const int cg8 = cg * 8;
  const int rg = tid >> 3;       // row group: rows rg*4 .. rg*4+3
  const int r0 = rg * 4;
  const int b0 = blockIdx.x * BPW;
  const int ub = tid >> 6;       // update-phase batch (== wave index)
  const int uj = tid & 63;       // update-phase hidden index (== lane)

  // ---- load weights into registers (once) ----
  float w1[4][8], w2[4][8], w3[4][8];  // Whh1, Wih2, Whh2 tiles
  float wi1[4], bb1[4], bb2[4];
#pragma unroll
  for (int rr = 0; rr < 4; ++rr) {
    const int r = r0 + rr;
#pragma unroll
    for (int cc = 0; cc < 8; ++cc) {
      w1[rr][cc] = Whh1[r * HID + cg8 + cc];
      w2[rr][cc] = Wih2[r * HID + cg8 + cc];
      w3[rr][cc] = Whh2[r * HID + cg8 + cc];
    }
    wi1[rr] = Wih1[r];  // F == 1
    bb1[rr] = bih1[r] + bhh1[r];
    bb2[rr] = bih2[r] + bhh2[r];
  }
  const float wlj = Wl[uj];
  const float blv = bl[0];
  const int nfut = future[0];

  // ---- stage input (transposed) + zero h ----
  {
    const float* src = input + (size_t)b0 * TSTEPS;  // F==1, row-major [B][T]
    for (int idx = tid; idx < BPW * TSTEPS; idx += TW) {
      int bi = idx >> 10;
      int t = idx & (TSTEPS - 1);
      s.xin[t][bi] = src[idx];
    }
    for (int idx = tid; idx < BPW * HID; idx += TW) {
      (&s.h1[0][0])[idx] = 0.0f;
      (&s.h2[0][0])[idx] = 0.0f;
    }
  }
  float c1 = 0.0f, c2 = 0.0f, h2r = 0.0f;
  __syncthreads();

  const int total = TSTEPS + nfut;
  for (int sidx = 0; sidx < total; ++sidx) {
    const int xt = (sidx < TSTEPS) ? sidx : TSTEPS;

    // ---- Phase A: acc1 = Whh1 @ h1_old ; acc2 = Whh2 @ h2_old ----
    float acc1[8][4], acc2[8][4];
#pragma unroll
    for (int b = 0; b < 8; ++b) {
      float4 ha = *(const float4*)&s.h1[b][cg8];
      float4 hb = *(const float4*)&s.h1[b][cg8 + 4];
      float4 ga = *(const float4*)&s.h2[b][cg8];
      float4 gb = *(const float4*)&s.h2[b][cg8 + 4];
#pragma unroll
      for (int rr = 0; rr < 4; ++rr) {
        acc1[b][rr] = dot8a(w1[rr], ha, hb, 0.0f);
        acc2[b][rr] = dot8a(w3[rr], ga, gb, 0.0f);
      }
    }
    float v1[4];
    rscat8(acc1, v1, cg);
    const float xv = s.xin[xt][cg];
#pragma unroll
    for (int rr = 0; rr < 4; ++rr) v1[rr] = v1[rr] + bb1[rr] + xv * wi1[rr];
    *(float4*)&s.g1[cg][r0] = make_float4(v1[0], v1[1], v1[2], v1[3]);
    __syncthreads();

    // ---- Phase B: update h1, c1 (thread owns (ub, uj)) ----
    {
      float gi = s.g1[ub][uj];
      float gf = s.g1[ub][64 + uj];
      float gg = s.g1[ub][128 + uj];
      float go = s.g1[ub][192 + uj];
      c1 = sigf(gf) * c1 + sigf(gi) * tanhfast(gg);
      float h1n = sigf(go) * tanhfast(c1);
      s.h1[ub][uj] = h1n;
    }
    __syncthreads();

    // ---- Phase C: acc2 += Wih2 @ h1_new ; write gates2 ----
#pragma unroll
    for (int b = 0; b < 8; ++b) {
      float4 ha = *(const float4*)&s.h1[b][cg8];
      float4 hb = *(const float4*)&s.h1[b][cg8 + 4];
#pragma unroll
      for (int rr = 0; rr < 4; ++rr) {
        acc2[b][rr] = dot8a(w2[rr], ha, hb, acc2[b][rr]);
      }
    }
    float v2[4];
    rscat8(acc2, v2, cg);
#pragma unroll
    for (int rr = 0; rr < 4; ++rr) v2[rr] += bb2[rr];
    *(float4*)&s.g2[cg][r0] = make_float4(v2[0], v2[1], v2[2], v2[3]);
    __syncthreads();

    // ---- Phase D: update h2, c2 ----
    {
      float gi = s.g2[ub][uj];
      float gf = s.g2[ub][64 + uj];
      float gg = s.g2[ub][128 + uj];
      float go = s.g2[ub][192 + uj];
      c2 = sigf(gf) * c2 + sigf(gi) * tanhfast(gg);
      h2r = sigf(go) * tanhfast(c2);
      s.h2[ub][uj] = h2r;
    }
    __syncthreads();

    // ---- Readout (after last main step and after every future step) ----
    if (sidx >= TSTEPS - 1) {
      float v = wlj * h2r;
#pragma unroll
      for (int m = 1; m < 64; m <<= 1) v += __shfl_xor(v, m, 64);
      if (uj == 0) s.xin[TSTEPS][ub] = v + blv;
      __syncthreads();
    }
  }

  if (uj == 0) out[b0 + ub] = s.xin[TSTEPS][ub];
}

extern "C" void kernel_launch(void* const* d_in, const int* in_sizes, int n_in,
                              void* d_out, int out_size, void* d_ws,
                              size_t ws_size, hipStream_t stream) {
  const float* input = (const float*)d_in[0];
  const float* Wih1 = (const float*)d_in[1];
  const float* Whh1 = (const float*)d_in[2];
  const float* bih1 = (const float*)d_in[3];
  const float* bhh1 = (const float*)d_in[4];
  const float* Wih2 = (const float*)d_in[5];
  const float* Whh2 = (const float*)d_in[6];
  const float* bih2 = (const float*)d_in[7];
  const float* bhh2 = (const float*)d_in[8];
  const float* Wl = (const float*)d_in[9];
  const float* bl = (const float*)d_in[10];
  const int* fut = (const int*)d_in[11];
  float* out = (float*)d_out;

  const int B = in_sizes[0] / TSTEPS;  // F == 1
  const int blocks = B / BPW;          // 2048/8 = 256 (one per CU)

  hipLaunchKernelGGL(lstm2_kernel, dim3(blocks), dim3(TW), 0, stream, input,
                     Wih1, Whh1, bih1, bhh1, Wih2, Whh2, bih2, bhh2, Wl, bl,
                     fut, out);
}

// Round 2
// 4868.415 us; speedup vs baseline: 1.0525x; 1.0525x over previous
//
#include <hip/hip_runtime.h>

#define HID 64
#define HPAD 68         // +4 pad: h write 2-way conflict (free), float4 reads 2-way
#define TSTEPS 1024
#define BPW 8           // batch elements per workgroup
#define TW 512          // threads per workgroup (8 waves)

__device__ __forceinline__ float sigf(float x) {
  return 1.0f / (1.0f + __expf(-x));
}
__device__ __forceinline__ float tanhfast(float x) {
  return 1.0f - 2.0f / (1.0f + __expf(2.0f * x));
}

struct __align__(16) SMem {
  float xin[TSTEPS + 1][BPW];  // transposed input; slot [TSTEPS] = future-step x
  float h1[2][BPW][HPAD];      // ping-pong buffers
  float h2[2][BPW][HPAD];
};

__device__ __forceinline__ float dot8a(const float (&w)[8], const float4& a,
                                       const float4& b, float s0) {
  float s = fmaf(w[0], a.x, s0);
  s = fmaf(w[1], a.y, s);
  s = fmaf(w[2], a.z, s);
  s = fmaf(w[3], a.w, s);
  s = fmaf(w[4], b.x, s);
  s = fmaf(w[5], b.y, s);
  s = fmaf(w[6], b.z, s);
  s = fmaf(w[7], b.w, s);
  return s;
}

// Reduce over the 8-lane column octet while scattering the batch index:
// thread with column-group cg ends with out[r] = sum over octet of a[cg][r].
// All static register indices; selection via per-lane ternary (v_cndmask).
__device__ __forceinline__ void rscat8(const float (&a)[8][4], float (&out)[4],
                                       int cg) {
  float p[8][4];
#pragma unroll
  for (int b = 0; b < 8; ++b)
#pragma unroll
    for (int r = 0; r < 4; ++r) p[b][r] = __shfl_xor(a[b][r], 1, 64);
  const bool s0 = (cg & 1) != 0;
  float t1[4][4];
#pragma unroll
  for (int k = 0; k < 4; ++k)
#pragma unroll
    for (int r = 0; r < 4; ++r) {
      float e = a[2 * k][r] + p[2 * k][r];
      float o = a[2 * k + 1][r] + p[2 * k + 1][r];
      t1[k][r] = s0 ? o : e;
    }
  float p1[4][4];
#pragma unroll
  for (int k = 0; k < 4; ++k)
#pragma unroll
    for (int r = 0; r < 4; ++r) p1[k][r] = __shfl_xor(t1[k][r], 2, 64);
  const bool s1 = (cg & 2) != 0;
  float t2[2][4];
#pragma unroll
  for (int k = 0; k < 2; ++k)
#pragma unroll
    for (int r = 0; r < 4; ++r) {
      float e = t1[2 * k][r] + p1[2 * k][r];
      float o = t1[2 * k + 1][r] + p1[2 * k + 1][r];
      t2[k][r] = s1 ? o : e;
    }
  float p2[2][4];
#pragma unroll
  for (int k = 0; k < 2; ++k)
#pragma unroll
    for (int r = 0; r < 4; ++r) p2[k][r] = __shfl_xor(t2[k][r], 4, 64);
  const bool s2 = (cg & 4) != 0;
#pragma unroll
  for (int r = 0; r < 4; ++r) {
    float e = t2[0][r] + p2[0][r];
    float o = t2[1][r] + p2[1][r];
    out[r] = s2 ? o : e;
  }
}

__global__ __launch_bounds__(TW, 2) void lstm2_kernel(
    const float* __restrict__ input, const float* __restrict__ Wih1,
    const float* __restrict__ Whh1, const float* __restrict__ bih1,
    const float* __restrict__ bhh1, const float* __restrict__ Wih2,
    const float* __restrict__ Whh2, const float* __restrict__ bih2,
    const float* __restrict__ bhh2, const float* __restrict__ Wl,
    const float* __restrict__ bl, const int* __restrict__ future,
    float* __restrict__ out) {
  __shared__ SMem s;
  const int tid = threadIdx.x;
  const int cg = tid & 7;        // column group: cols cg*8 .. cg*8+7
  const int cg8 = cg * 8;
  const int rg = tid >> 3;       // gate-aligned row: rows {rg, 64+rg, 128+rg, 192+rg}
  const int b0 = blockIdx.x * BPW;
  const int ub = tid >> 6;       // readout batch (== wave index)
  const int uj = tid & 63;       // readout hidden index (== lane)

  // ---- load weights into registers (gate-aligned rows) ----
  float w1[4][8], w2[4][8], w3[4][8];  // Whh1, Wih2, Whh2 tiles
  float wi1[4], bb1[4], bb2[4];
#pragma unroll
  for (int q = 0; q < 4; ++q) {
    const int r = q * HID + rg;  // gate q, hidden j = rg
#pragma unroll
    for (int cc = 0; cc < 8; ++cc) {
      w1[q][cc] = Whh1[r * HID + cg8 + cc];
      w2[q][cc] = Wih2[r * HID + cg8 + cc];
      w3[q][cc] = Whh2[r * HID + cg8 + cc];
    }
    wi1[q] = Wih1[r];  // F == 1
    bb1[q] = bih1[r] + bhh1[r];
    bb2[q] = bih2[r] + bhh2[r];
  }
  const float wlj = Wl[uj];
  const float blv = bl[0];
  const int nfut = future[0];

  // ---- stage input (transposed) + zero h buffers ----
  {
    const float* src = input + (size_t)b0 * TSTEPS;  // F==1, row-major [B][T]
    for (int idx = tid; idx < BPW * TSTEPS; idx += TW) {
      int bi = idx >> 10;
      int t = idx & (TSTEPS - 1);
      s.xin[t][bi] = src[idx];
    }
    float* hz1 = &s.h1[0][0][0];
    float* hz2 = &s.h2[0][0][0];
    for (int idx = tid; idx < 2 * BPW * HPAD; idx += TW) {
      hz1[idx] = 0.0f;
      hz2[idx] = 0.0f;
    }
  }
  float c1 = 0.0f, c2 = 0.0f;
  __syncthreads();

  const int total = TSTEPS + nfut;
  for (int sidx = 0; sidx < total; ++sidx) {
    const int p = sidx & 1, pn = p ^ 1;
    const int xt = (sidx < TSTEPS) ? sidx : TSTEPS;

    // ---- Layer-1 partials: acc1 = Whh1 @ h1_old ; acc2 = Whh2 @ h2_old ----
    float acc1[8][4], acc2[8][4];
#pragma unroll
    for (int b = 0; b < 8; ++b) {
      float4 ha = *(const float4*)&s.h1[p][b][cg8];
      float4 hb = *(const float4*)&s.h1[p][b][cg8 + 4];
      float4 ga = *(const float4*)&s.h2[p][b][cg8];
      float4 gb = *(const float4*)&s.h2[p][b][cg8 + 4];
#pragma unroll
      for (int q = 0; q < 4; ++q) {
        acc1[b][q] = dot8a(w1[q], ha, hb, 0.0f);
        acc2[b][q] = dot8a(w3[q], ga, gb, 0.0f);
      }
    }
    float v1[4];
    rscat8(acc1, v1, cg);
    const float xv = s.xin[xt][cg];
#pragma unroll
    for (int q = 0; q < 4; ++q) v1[q] = v1[q] + bb1[q] + xv * wi1[q];
    // gates (i,f,g,o) for (batch cg, j rg) — register-local update
    c1 = sigf(v1[1]) * c1 + sigf(v1[0]) * tanhfast(v1[2]);
    s.h1[pn][cg][rg] = sigf(v1[3]) * tanhfast(c1);
    __syncthreads();

    // ---- Layer-2: acc2 += Wih2 @ h1_new ----
#pragma unroll
    for (int b = 0; b < 8; ++b) {
      float4 ha = *(const float4*)&s.h1[pn][b][cg8];
      float4 hb = *(const float4*)&s.h1[pn][b][cg8 + 4];
#pragma unroll
      for (int q = 0; q < 4; ++q) {
        acc2[b][q] = dot8a(w2[q], ha, hb, acc2[b][q]);
      }
    }
    float v2[4];
    rscat8(acc2, v2, cg);
#pragma unroll
    for (int q = 0; q < 4; ++q) v2[q] += bb2[q];
    c2 = sigf(v2[1]) * c2 + sigf(v2[0]) * tanhfast(v2[2]);
    s.h2[pn][cg][rg] = sigf(v2[3]) * tanhfast(c2);
    __syncthreads();

    // ---- Readout (last main step and every future step) ----
    if (sidx >= TSTEPS - 1) {
      float v = wlj * s.h2[pn][ub][uj];
#pragma unroll
      for (int m = 1; m < 64; m <<= 1) v += __shfl_xor(v, m, 64);
      if (uj == 0) s.xin[TSTEPS][ub] = v + blv;
      __syncthreads();
    }
  }

  if (uj == 0) out[b0 + ub] = s.xin[TSTEPS][ub];
}

extern "C" void kernel_launch(void* const* d_in, const int* in_sizes, int n_in,
                              void* d_out, int out_size, void* d_ws,
                              size_t ws_size, hipStream_t stream) {
  const float* input = (const float*)d_in[0];
  const float* Wih1 = (const float*)d_in[1];
  const float* Whh1 = (const float*)d_in[2];
  const float* bih1 = (const float*)d_in[3];
  const float* bhh1 = (const float*)d_in[4];
  const float* Wih2 = (const float*)d_in[5];
  const float* Whh2 = (const float*)d_in[6];
  const float* bih2 = (const float*)d_in[7];
  const float* bhh2 = (const float*)d_in[8];
  const float* Wl = (const float*)d_in[9];
  const float* bl = (const float*)d_in[10];
  const int* fut = (const int*)d_in[11];
  float* out = (float*)d_out;

  const int B = in_sizes[0] / TSTEPS;  // F == 1
  const int blocks = B / BPW;          // 2048/8 = 256 (one per CU)

  hipLaunchKernelGGL(lstm2_kernel, dim3(blocks), dim3(TW), 0, stream, input,
                     Wih1, Whh1, bih1, bhh1, Wih2, Whh2, bih2, bhh2, Wl, bl,
                     fut, out);
}

// Round 3
// 3442.770 us; speedup vs baseline: 1.4884x; 1.4141x over previous
//
#include <hip/hip_runtime.h>

#define HID 64
#define HPAD 68         // +4 pad: h write 2-way conflict (free), float4 reads 2-way
#define TSTEPS 1024
#define BPW 8           // batch elements per workgroup
#define TW 512          // threads per workgroup (8 waves)

__device__ __forceinline__ float sigf(float x) {
  return 1.0f / (1.0f + __expf(-x));
}
__device__ __forceinline__ float tanhfast(float x) {
  return 1.0f - 2.0f / (1.0f + __expf(2.0f * x));
}

struct __align__(16) SMem {
  float xin[TSTEPS + 1][BPW];  // transposed input; slot [TSTEPS] = future-step x
  float h1[2][BPW][HPAD];      // ping-pong buffers
  float h2[2][BPW][HPAD];
};

// x + shuffle_xor1(x) via DPP quad_perm [1,0,3,2] — pure VALU, no DS pipe.
__device__ __forceinline__ float dppadd_xor1(float x) {
  int xi = __float_as_int(x);
  int sh = __builtin_amdgcn_update_dpp(xi, xi, 0xB1, 0xF, 0xF, true);
  return x + __int_as_float(sh);
}
// x + shuffle_xor2(x) via DPP quad_perm [2,3,0,1]
__device__ __forceinline__ float dppadd_xor2(float x) {
  int xi = __float_as_int(x);
  int sh = __builtin_amdgcn_update_dpp(xi, xi, 0x4E, 0xF, 0xF, true);
  return x + __int_as_float(sh);
}
// x + shuffle_xor4(x) via ds_swizzle BitMode (xor_mask=4, and=0x1F)
__device__ __forceinline__ float swzadd_xor4(float x) {
  int xi = __float_as_int(x);
  int sh = __builtin_amdgcn_ds_swizzle(xi, 0x101F);
  return x + __int_as_float(sh);
}

// Reduce over the 8-lane column octet while scattering the batch index:
// thread with column-group cg ends with out[r] = sum over octet of a[cg][r].
__device__ __forceinline__ void rscat8(const float (&a)[8][4], float (&out)[4],
                                       int cg) {
  const bool s0 = (cg & 1) != 0;
  const bool s1 = (cg & 2) != 0;
  const bool s2 = (cg & 4) != 0;
  float t1[4][4];
#pragma unroll
  for (int k = 0; k < 4; ++k)
#pragma unroll
    for (int r = 0; r < 4; ++r) {
      float e = dppadd_xor1(a[2 * k][r]);
      float o = dppadd_xor1(a[2 * k + 1][r]);
      t1[k][r] = s0 ? o : e;
    }
  float t2[2][4];
#pragma unroll
  for (int k = 0; k < 2; ++k)
#pragma unroll
    for (int r = 0; r < 4; ++r) {
      float e = dppadd_xor2(t1[2 * k][r]);
      float o = dppadd_xor2(t1[2 * k + 1][r]);
      t2[k][r] = s1 ? o : e;
    }
#pragma unroll
  for (int r = 0; r < 4; ++r) {
    float e = swzadd_xor4(t2[0][r]);
    float o = swzadd_xor4(t2[1][r]);
    out[r] = s2 ? o : e;
  }
}

__device__ __forceinline__ float dot8a(const float (&w)[8], const float4& a,
                                       const float4& b, float s0) {
  float s = fmaf(w[0], a.x, s0);
  s = fmaf(w[1], a.y, s);
  s = fmaf(w[2], a.z, s);
  s = fmaf(w[3], a.w, s);
  s = fmaf(w[4], b.x, s);
  s = fmaf(w[5], b.y, s);
  s = fmaf(w[6], b.z, s);
  s = fmaf(w[7], b.w, s);
  return s;
}

// Pin 8 floats into VGPRs: opaque asm result cannot be rematerialized, so the
// register allocator must keep them live instead of re-loading from global
// every step (round-2 pathology: VGPR_Count=104 with 96 weights in source).
#define PIN8(r)                                                            \
  asm volatile("" : "+v"(r[0]), "+v"(r[1]), "+v"(r[2]), "+v"(r[3]),        \
                    "+v"(r[4]), "+v"(r[5]), "+v"(r[6]), "+v"(r[7]))
#define PIN4(r) asm volatile("" : "+v"(r[0]), "+v"(r[1]), "+v"(r[2]), "+v"(r[3]))

__global__ __launch_bounds__(TW, 2) void lstm2_kernel(
    const float* __restrict__ input, const float* __restrict__ Wih1,
    const float* __restrict__ Whh1, const float* __restrict__ bih1,
    const float* __restrict__ bhh1, const float* __restrict__ Wih2,
    const float* __restrict__ Whh2, const float* __restrict__ bih2,
    const float* __restrict__ bhh2, const float* __restrict__ Wl,
    const float* __restrict__ bl, const int* __restrict__ future,
    float* __restrict__ out) {
  __shared__ SMem s;
  const int tid = threadIdx.x;
  const int cg = tid & 7;        // column group: cols cg*8 .. cg*8+7
  const int cg8 = cg * 8;
  const int rg = tid >> 3;       // gate-aligned row: rows {rg, 64+rg, 128+rg, 192+rg}
  const int b0 = blockIdx.x * BPW;
  const int ub = tid >> 6;       // readout batch (== wave index)
  const int uj = tid & 63;       // readout hidden index (== lane)

  // ---- load weights into registers (gate-aligned rows) ----
  float w1[4][8], w2[4][8], w3[4][8];  // Whh1, Wih2, Whh2 tiles
  float wi1[4], bb1[4], bb2[4];
#pragma unroll
  for (int q = 0; q < 4; ++q) {
    const int r = q * HID + rg;  // gate q, hidden j = rg
#pragma unroll
    for (int cc = 0; cc < 8; ++cc) {
      w1[q][cc] = Whh1[r * HID + cg8 + cc];
      w2[q][cc] = Wih2[r * HID + cg8 + cc];
      w3[q][cc] = Whh2[r * HID + cg8 + cc];
    }
    wi1[q] = Wih1[r];  // F == 1
    bb1[q] = bih1[r] + bhh1[r];
    bb2[q] = bih2[r] + bhh2[r];
  }
#pragma unroll
  for (int q = 0; q < 4; ++q) {
    PIN8(w1[q]);
    PIN8(w2[q]);
    PIN8(w3[q]);
  }
  PIN4(wi1);
  PIN4(bb1);
  PIN4(bb2);
  const float wlj = Wl[uj];
  const float blv = bl[0];
  const int nfut = future[0];

  // ---- stage input (transposed) + zero h buffers ----
  {
    const float* src = input + (size_t)b0 * TSTEPS;  // F==1, row-major [B][T]
    for (int idx = tid; idx < BPW * TSTEPS; idx += TW) {
      int bi = idx >> 10;
      int t = idx & (TSTEPS - 1);
      s.xin[t][bi] = src[idx];
    }
    float* hz1 = &s.h1[0][0][0];
    float* hz2 = &s.h2[0][0][0];
    for (int idx = tid; idx < 2 * BPW * HPAD; idx += TW) {
      hz1[idx] = 0.0f;
      hz2[idx] = 0.0f;
    }
  }
  float c1 = 0.0f, c2 = 0.0f;
  __syncthreads();

  const int total = TSTEPS + nfut;
  for (int sidx = 0; sidx < total; ++sidx) {
    const int p = sidx & 1, pn = p ^ 1;
    const int xt = (sidx < TSTEPS) ? sidx : TSTEPS;

    // ---- Layer-1 partials: acc1 = Whh1 @ h1_old ; acc2 = Whh2 @ h2_old ----
    float acc1[8][4], acc2[8][4];
#pragma unroll
    for (int b = 0; b < 8; ++b) {
      float4 ha = *(const float4*)&s.h1[p][b][cg8];
      float4 hb = *(const float4*)&s.h1[p][b][cg8 + 4];
      float4 ga = *(const float4*)&s.h2[p][b][cg8];
      float4 gb = *(const float4*)&s.h2[p][b][cg8 + 4];
#pragma unroll
      for (int q = 0; q < 4; ++q) {
        acc1[b][q] = dot8a(w1[q], ha, hb, 0.0f);
        acc2[b][q] = dot8a(w3[q], ga, gb, 0.0f);
      }
    }
    float v1[4];
    rscat8(acc1, v1, cg);
    const float xv = s.xin[xt][cg];
#pragma unroll
    for (int q = 0; q < 4; ++q) v1[q] = v1[q] + bb1[q] + xv * wi1[q];
    // gates (i,f,g,o) for (batch cg, j rg) — register-local update
    c1 = sigf(v1[1]) * c1 + sigf(v1[0]) * tanhfast(v1[2]);
    s.h1[pn][cg][rg] = sigf(v1[3]) * tanhfast(c1);
    __syncthreads();

    // ---- Layer-2: acc2 += Wih2 @ h1_new ----
#pragma unroll
    for (int b = 0; b < 8; ++b) {
      float4 ha = *(const float4*)&s.h1[pn][b][cg8];
      float4 hb = *(const float4*)&s.h1[pn][b][cg8 + 4];
#pragma unroll
      for (int q = 0; q < 4; ++q) {
        acc2[b][q] = dot8a(w2[q], ha, hb, acc2[b][q]);
      }
    }
    float v2[4];
    rscat8(acc2, v2, cg);
#pragma unroll
    for (int q = 0; q < 4; ++q) v2[q] += bb2[q];
    c2 = sigf(v2[1]) * c2 + sigf(v2[0]) * tanhfast(v2[2]);
    s.h2[pn][cg][rg] = sigf(v2[3]) * tanhfast(c2);
    __syncthreads();

    // ---- Readout (last main step and every future step) ----
    if (sidx >= TSTEPS - 1) {
      float v = wlj * s.h2[pn][ub][uj];
#pragma unroll
      for (int m = 1; m < 64; m <<= 1) v += __shfl_xor(v, m, 64);
      if (uj == 0) s.xin[TSTEPS][ub] = v + blv;
      __syncthreads();
    }
  }

  if (uj == 0) out[b0 + ub] = s.xin[TSTEPS][ub];
}

extern "C" void kernel_launch(void* const* d_in, const int* in_sizes, int n_in,
                              void* d_out, int out_size, void* d_ws,
                              size_t ws_size, hipStream_t stream) {
  const float* input = (const float*)d_in[0];
  const float* Wih1 = (const float*)d_in[1];
  const float* Whh1 = (const float*)d_in[2];
  const float* bih1 = (const float*)d_in[3];
  const float* bhh1 = (const float*)d_in[4];
  const float* Wih2 = (const float*)d_in[5];
  const float* Whh2 = (const float*)d_in[6];
  const float* bih2 = (const float*)d_in[7];
  const float* bhh2 = (const float*)d_in[8];
  const float* Wl = (const float*)d_in[9];
  const float* bl = (const float*)d_in[10];
  const int* fut = (const int*)d_in[11];
  float* out = (float*)d_out;

  const int B = in_sizes[0] / TSTEPS;  // F == 1
  const int blocks = B / BPW;          // 2048/8 = 256 (one per CU)

  hipLaunchKernelGGL(lstm2_kernel, dim3(blocks), dim3(TW), 0, stream, input,
                     Wih1, Whh1, bih1, bhh1, Wih2, Whh2, bih2, bhh2, Wl, bl,
                     fut, out);
}

// Round 4
// 923.106 us; speedup vs baseline: 5.5509x; 3.7296x over previous
//
#include <hip/hip_runtime.h>

#define HID 64
#define TSTEPS 1024
#define BPW 8            // batch elements per workgroup
#define TW 512           // 8 waves

typedef __attribute__((ext_vector_type(8))) short short8v;   // 8 bf16
typedef __attribute__((ext_vector_type(4))) float f32x4;

__device__ __forceinline__ unsigned short f2bf(float f) {
  unsigned u = __float_as_uint(f);
  u += 0x7FFFu + ((u >> 16) & 1u);
  return (unsigned short)(u >> 16);
}
__device__ __forceinline__ float bf2f(unsigned short h) {
  return __uint_as_float(((unsigned)h) << 16);
}
__device__ __forceinline__ float sigf(float x) {
  return __builtin_amdgcn_rcpf(1.0f + __expf(-x));
}
__device__ __forceinline__ float tanh_(float x) {
  return 1.0f - 2.0f * __builtin_amdgcn_rcpf(1.0f + __expf(2.0f * x));
}
// x + (value from lane^8): row_ror:8 within each 16-lane row (pure VALU)
__device__ __forceinline__ float dppror8(float x) {
  int xi = __float_as_int(x);
  int y = __builtin_amdgcn_update_dpp(xi, xi, 0x128, 0xF, 0xF, true);
  return __int_as_float(y);
}
__device__ __forceinline__ f32x4 mf(short8v a, short8v b, f32x4 c) {
  return __builtin_amdgcn_mfma_f32_16x16x32_bf16(a, b, c, 0, 0, 0);
}
// B-fragment buffers, stored in exact MFMA-B lane order with XOR bank swizzle.
__device__ __forceinline__ short8v ld_frag(const short* buf, int ss, int lane) {
  int byte = (ss * 64 + lane) * 16;
  byte ^= ((byte >> 7) & 7) << 4;
  return *(const short8v*)((const char*)buf + byte);
}
__device__ __forceinline__ void st_frag32(short* buf, int jj, int col, unsigned v) {
  int byte = (((jj >> 5) * 64 + ((jj & 31) >> 3) * 16 + col) * 8 + (jj & 7)) * 2;
  byte ^= ((byte >> 7) & 7) << 4;
  *(unsigned*)((char*)buf + byte) = v;
}
// load 8 consecutive f32, split into bf16 hi/lo fragments
__device__ __forceinline__ void load8split(const float* rp, short8v& hi, short8v& lo) {
  float t[8];
#pragma unroll
  for (int e = 0; e < 8; ++e) t[e] = rp[e];
#pragma unroll
  for (int e = 0; e < 8; ++e) {
    unsigned short h = f2bf(t[e]);
    hi[e] = (short)h;
    lo[e] = (short)f2bf(t[e] - bf2f(h));
  }
}
__device__ __forceinline__ float cellup(float zi, float zf, float zg, float zo,
                                        float& c) {
  c = sigf(zf) * c + sigf(zi) * tanh_(zg);
  return sigf(zo) * tanh_(c);
}

struct __align__(128) SMem {
  float xin[TSTEPS + 1][BPW];   // transposed input; slot TSTEPS = future x
  short hf1[2][1024];           // h1 B-frags [parity][(s*64+lane)*8+e], swizzled
  short hf2[2][1024];           // h2 B-frags
  float ro[4][BPW];             // readout partials
};

__global__ __launch_bounds__(TW, 2) void lstm2_kernel(
    const float* __restrict__ input, const float* __restrict__ Wih1,
    const float* __restrict__ Whh1, const float* __restrict__ bih1,
    const float* __restrict__ bhh1, const float* __restrict__ Wih2,
    const float* __restrict__ Whh2, const float* __restrict__ bih2,
    const float* __restrict__ bhh2, const float* __restrict__ Wl,
    const float* __restrict__ bl, const int* __restrict__ future,
    float* __restrict__ out) {
  __shared__ SMem s;
  const int tid = threadIdx.x;
  const int w = tid >> 6;
  const int lane = tid & 63;
  const int wq = w & 3;
  const int b = lane & 7;          // batch (C col, hi half)
  const int d = (lane >> 3) & 1;   // row-pair select
  const int g = lane >> 4;         // C row group
  const int j0 = 16 * wq + 4 * g + 2 * d;  // this lane owns j0, j0+1
  const int b0 = blockIdx.x * BPW;
  const bool isL1 = (w < 4);

  // ---- weight fragments (A-operand, registers) ----
  // WA: phase-A matrix (Whh2; unused results for waves 0-3)
  // WC: phase-C matrix (Whh1 for waves 0-3, Wih2 for waves 4-7)
  short8v WAh[4][2], WAl[4][2], WCh[4][2], WCl[4][2];
  const float* WCsrc = isL1 ? Whh1 : Wih2;
  const float* WAsrc = Whh2;
#pragma unroll
  for (int q = 0; q < 4; ++q) {
    const int m = (4 * q + wq) * 16 + (lane & 15);
    const int koff = (lane >> 4) * 8;
#pragma unroll
    for (int ss = 0; ss < 2; ++ss) {
      load8split(WCsrc + m * HID + ss * 32 + koff, WCh[q][ss], WCl[q][ss]);
      load8split(WAsrc + m * HID + ss * 32 + koff, WAh[q][ss], WAl[q][ss]);
    }
  }
#pragma unroll
  for (int q = 0; q < 4; ++q)
#pragma unroll
    for (int ss = 0; ss < 2; ++ss)
      asm volatile("" : "+v"(WAh[q][ss]), "+v"(WAl[q][ss]),
                        "+v"(WCh[q][ss]), "+v"(WCl[q][ss]));

  // ---- biases / vectors for this lane's two (b, j) pairs ----
  const float* biA = isL1 ? bih1 : bih2;
  const float* biB = isL1 ? bhh1 : bhh2;
  float bb[4][2], wi[4][2];
#pragma unroll
  for (int q = 0; q < 4; ++q)
#pragma unroll
    for (int i = 0; i < 2; ++i) {
      const int row = 64 * q + j0 + i;
      bb[q][i] = biA[row] + biB[row];
      wi[q][i] = isL1 ? Wih1[row] : 0.0f;
    }
  const float wl0 = isL1 ? 0.0f : Wl[j0];
  const float wl1 = isL1 ? 0.0f : Wl[j0 + 1];
  const float blv = bl[0];
  const int nfut = future[0];

  // ---- stage input (transposed) + zero frag buffers ----
  {
    const float* src = input + (size_t)b0 * TSTEPS;  // F==1, [B][T]
    for (int idx = tid; idx < BPW * TSTEPS; idx += TW) {
      int bi = idx >> 10;
      int t = idx & (TSTEPS - 1);
      s.xin[t][bi] = src[idx];
    }
    for (int idx = tid; idx < 2 * 1024; idx += TW) {
      ((short*)s.hf1)[idx] = 0;
      ((short*)s.hf2)[idx] = 0;
    }
  }
  f32x4 acc[4];
#pragma unroll
  for (int q = 0; q < 4; ++q) acc[q] = (f32x4){0.f, 0.f, 0.f, 0.f};
  float cA = 0.f, cB = 0.f;   // cell states for lane's two j's
  float hn0 = 0.f, hn1 = 0.f; // layer-2 h (waves 4-7)
  __syncthreads();

  const int total = TSTEPS + nfut;
  const f32x4 zf = (f32x4){0.f, 0.f, 0.f, 0.f};
  for (int sidx = 0; sidx < total; ++sidx) {
    const int p = sidx & 1, pn = p ^ 1;

    // ================= phase A =================
    if (isL1) {
      // gates1: acc holds Whh1 @ h1(t-1) (from previous phase C; step0: 0)
      float z0[4], z1[4];
#pragma unroll
      for (int q = 0; q < 4; ++q) {
        float s0 = acc[q][0] + dppror8(acc[q][0]);
        float s1 = acc[q][1] + dppror8(acc[q][1]);
        float s2 = acc[q][2] + dppror8(acc[q][2]);
        float s3 = acc[q][3] + dppror8(acc[q][3]);
        z0[q] = d ? s2 : s0;
        z1[q] = d ? s3 : s1;
      }
      const int xt = (sidx < TSTEPS) ? sidx : TSTEPS;
      const float xv = s.xin[xt][b];
#pragma unroll
      for (int q = 0; q < 4; ++q) {
        z0[q] += bb[q][0] + xv * wi[q][0];
        z1[q] += bb[q][1] + xv * wi[q][1];
      }
      float h0 = cellup(z0[0], z0[1], z0[2], z0[3], cA);
      float h1v = cellup(z1[0], z1[1], z1[2], z1[3], cB);
      unsigned short h0h = f2bf(h0), h1h = f2bf(h1v);
      unsigned short h0l = f2bf(h0 - bf2f(h0h));
      unsigned short h1l = f2bf(h1v - bf2f(h1h));
      st_frag32(s.hf1[pn], j0, b, (unsigned)h0h | ((unsigned)h1h << 16));
      st_frag32(s.hf1[pn], j0, b + 8, (unsigned)h0l | ((unsigned)h1l << 16));
    } else {
      // Whh2 @ h2(t-1)
      short8v B0 = ld_frag(s.hf2[p], 0, lane);
      short8v B1 = ld_frag(s.hf2[p], 1, lane);
#pragma unroll
      for (int q = 0; q < 4; ++q)
        acc[q] = mf(WAh[q][1], B1,
                    mf(WAl[q][1], B1, mf(WAh[q][0], B0, mf(WAl[q][0], B0, zf))));
    }
    __syncthreads();

    // ================= phase C =================
    {
      short8v B0 = ld_frag(s.hf1[pn], 0, lane);
      short8v B1 = ld_frag(s.hf1[pn], 1, lane);
      if (isL1) {
        // next step's Whh1 @ h1(t)
#pragma unroll
        for (int q = 0; q < 4; ++q)
          acc[q] = mf(WCh[q][1], B1,
                      mf(WCl[q][1], B1, mf(WCh[q][0], B0, mf(WCl[q][0], B0, zf))));
      } else {
        // z2 = Whh2@h2(t-1) + Wih2@h1(t)
#pragma unroll
        for (int q = 0; q < 4; ++q)
          acc[q] = mf(WCh[q][1], B1,
                      mf(WCl[q][1], B1,
                         mf(WCh[q][0], B0, mf(WCl[q][0], B0, acc[q]))));
        float z0[4], z1[4];
#pragma unroll
        for (int q = 0; q < 4; ++q) {
          float s0 = acc[q][0] + dppror8(acc[q][0]);
          float s1 = acc[q][1] + dppror8(acc[q][1]);
          float s2 = acc[q][2] + dppror8(acc[q][2]);
          float s3 = acc[q][3] + dppror8(acc[q][3]);
          z0[q] = (d ? s2 : s0) + bb[q][0];
          z1[q] = (d ? s3 : s1) + bb[q][1];
        }
        hn0 = cellup(z0[0], z0[1], z0[2], z0[3], cA);
        hn1 = cellup(z1[0], z1[1], z1[2], z1[3], cB);
        unsigned short h0h = f2bf(hn0), h1h = f2bf(hn1);
        unsigned short h0l = f2bf(hn0 - bf2f(h0h));
        unsigned short h1l = f2bf(hn1 - bf2f(h1h));
        st_frag32(s.hf2[pn], j0, b, (unsigned)h0h | ((unsigned)h1h << 16));
        st_frag32(s.hf2[pn], j0, b + 8, (unsigned)h0l | ((unsigned)h1l << 16));
      }
    }

    // ---- readout (last main step + every future step) ----
    if (sidx >= TSTEPS - 1) {
      float v = isL1 ? 0.0f : (wl0 * hn0 + wl1 * hn1);
      v += __shfl_xor(v, 8, 64);
      v += __shfl_xor(v, 16, 64);
      v += __shfl_xor(v, 32, 64);
      if (!isL1 && lane < 8) s.ro[wq][lane] = v;
      __syncthreads();
      if (tid < 8)
        s.xin[TSTEPS][tid] =
            s.ro[0][tid] + s.ro[1][tid] + s.ro[2][tid] + s.ro[3][tid] + blv;
    }
    __syncthreads();
  }

  if (tid < 8) out[b0 + tid] = s.xin[TSTEPS][tid];
}

extern "C" void kernel_launch(void* const* d_in, const int* in_sizes, int n_in,
                              void* d_out, int out_size, void* d_ws,
                              size_t ws_size, hipStream_t stream) {
  const float* input = (const float*)d_in[0];
  const float* Wih1 = (const float*)d_in[1];
  const float* Whh1 = (const float*)d_in[2];
  const float* bih1 = (const float*)d_in[3];
  const float* bhh1 = (const float*)d_in[4];
  const float* Wih2 = (const float*)d_in[5];
  const float* Whh2 = (const float*)d_in[6];
  const float* bih2 = (const float*)d_in[7];
  const float* bhh2 = (const float*)d_in[8];
  const float* Wl = (const float*)d_in[9];
  const float* bl = (const float*)d_in[10];
  const int* fut = (const int*)d_in[11];
  float* out = (float*)d_out;

  const int B = in_sizes[0] / TSTEPS;  // F == 1
  const int blocks = B / BPW;          // 256 (one per CU)

  hipLaunchKernelGGL(lstm2_kernel, dim3(blocks), dim3(TW), 0, stream, input,
                     Wih1, Whh1, bih1, bhh1, Wih2, Whh2, bih2, bhh2, Wl, bl,
                     fut, out);
}